// Round 2
// baseline (638.666 us; speedup 1.0000x reference)
//
#include <hip/hip_runtime.h>
#include <hip/hip_bf16.h>

// AttentionLayer: T=128, N=2048, D=256, w=3
// out[i] = x[i]                                   for i < 3
// out[i,n,:] = sum_j p[i-3+j,n] * x[i-3+j,n,:]    for i >= 3
// p[t,:] = softmax_n( sum_e proj[e]*tanh( (x[t] @ W)[n,e] ) )

#define T_DIM 128
#define N_DIM 2048
#define D_DIM 256
#define TS 127              // s/p slices (t = 0..126)
#define M_TOT (TS * N_DIM)  // 260096 GEMM rows

typedef __attribute__((ext_vector_type(8))) short bf16x8;
typedef __attribute__((ext_vector_type(4))) float f32x4;

__device__ inline short f2bf(float f) {
  union { float f; unsigned u; } v; v.f = f;
  unsigned r = v.u + 0x7FFFu + ((v.u >> 16) & 1u);  // RNE
  return (short)(r >> 16);
}

__device__ inline bf16x8 cvt8(float4 u, float4 v) {
  bf16x8 r;
  r[0] = f2bf(u.x); r[1] = f2bf(u.y); r[2] = f2bf(u.z); r[3] = f2bf(u.w);
  r[4] = f2bf(v.x); r[5] = f2bf(v.y); r[6] = f2bf(v.z); r[7] = f2bf(v.w);
  return r;
}

// ---------------- k0: W (fp32, d x e) -> Wt (bf16, e x d) ----------------
__global__ __launch_bounds__(256) void prep_kernel(const float* __restrict__ W,
                                                   short* __restrict__ Wt) {
  int id = blockIdx.x * 256 + threadIdx.x;  // 65536
  int d = id >> 8;
  int e = id & 255;
  Wt[e * 256 + d] = f2bf(W[d * 256 + e]);
}

// ---------------- k1: register-tiled fused GEMM + tanh + proj-reduce -----
// Block = 4 waves, 64 m-rows. Wave: 32 m-rows x 128 e x K=256.
// No LDS staging, no K-loop barriers. A from global fp32 (cvt in reg),
// B-frags from L2-resident Wt. One barrier for the e-half reduce.
__global__ __launch_bounds__(256, 4) void gemm_s_kernel(const float* __restrict__ x,
                                                        const short* __restrict__ Wt,
                                                        const float* __restrict__ proj,
                                                        float* __restrict__ s) {
  __shared__ float sred[64][2];

  const int tid = threadIdx.x;
  const int lane = tid & 63;
  const int w = tid >> 6;
  const int quad = lane >> 4;
  const int l15 = lane & 15;
  const int mb = blockIdx.x * 64 + (w >> 1) * 32;  // wave's first m-row
  const int e0 = (w & 1) * 128;                    // wave's e-half

  f32x4 acc[2][8] = {};

  // A row pointers for the two 16-row fragments (fp32 source)
  const float* arow0 = x + (size_t)(mb + l15) * D_DIM + quad * 8;
  const float* arow1 = x + (size_t)(mb + 16 + l15) * D_DIM + quad * 8;
  // B frag base: Wt[(e0 + j*16 + l15)*256 + kk + quad*8]
  const short* bbase = Wt + (size_t)(e0 + l15) * D_DIM + quad * 8;

  // prefetch first A
  float4 af[2][2], an[2][2];
  af[0][0] = *(const float4*)(arow0 + 0);
  af[0][1] = *(const float4*)(arow0 + 4);
  af[1][0] = *(const float4*)(arow1 + 0);
  af[1][1] = *(const float4*)(arow1 + 4);

  for (int kk = 0; kk < D_DIM; kk += 32) {
    if (kk + 32 < D_DIM) {
      an[0][0] = *(const float4*)(arow0 + kk + 32);
      an[0][1] = *(const float4*)(arow0 + kk + 36);
      an[1][0] = *(const float4*)(arow1 + kk + 32);
      an[1][1] = *(const float4*)(arow1 + kk + 36);
    }
    bf16x8 a0 = cvt8(af[0][0], af[0][1]);
    bf16x8 a1 = cvt8(af[1][0], af[1][1]);
#pragma unroll
    for (int j = 0; j < 8; ++j) {
      bf16x8 b = *(const bf16x8*)(bbase + (size_t)j * 16 * D_DIM + kk);
      acc[0][j] = __builtin_amdgcn_mfma_f32_16x16x32_bf16(a0, b, acc[0][j], 0, 0, 0);
      acc[1][j] = __builtin_amdgcn_mfma_f32_16x16x32_bf16(a1, b, acc[1][j], 0, 0, 0);
    }
    af[0][0] = an[0][0]; af[0][1] = an[0][1];
    af[1][0] = an[1][0]; af[1][1] = an[1][1];
  }

  // epilogue: val[m] = sum_e tanh(C[m][e]) * proj[e] for this e-half
  float pj[8];
#pragma unroll
  for (int j = 0; j < 8; ++j) pj[j] = proj[e0 + j * 16 + l15];

#pragma unroll
  for (int i = 0; i < 2; ++i) {
#pragma unroll
    for (int r = 0; r < 4; ++r) {
      float val = 0.f;
#pragma unroll
      for (int j = 0; j < 8; ++j) val += tanhf(acc[i][j][r]) * pj[j];
#pragma unroll
      for (int off = 1; off < 16; off <<= 1) val += __shfl_xor(val, off);
      if (l15 == 0) sred[(w >> 1) * 32 + i * 16 + quad * 4 + r][w & 1] = val;
    }
  }
  __syncthreads();
  if (tid < 64) s[blockIdx.x * 64 + tid] = sred[tid][0] + sred[tid][1];
}

// ---------------- k2: softmax over n (2048) per t ------------------------
__global__ __launch_bounds__(256) void softmax_kernel(const float* __restrict__ s,
                                                      float* __restrict__ p) {
  const int t = blockIdx.x;
  const int tid = threadIdx.x;
  const float* row = s + (size_t)t * N_DIM;
  float v[8];
  float mx = -1e30f;
#pragma unroll
  for (int k = 0; k < 8; ++k) {
    v[k] = row[tid + k * 256];
    mx = fmaxf(mx, v[k]);
  }
#pragma unroll
  for (int off = 1; off < 64; off <<= 1) mx = fmaxf(mx, __shfl_xor(mx, off));
  __shared__ float redm[4];
  if ((tid & 63) == 0) redm[tid >> 6] = mx;
  __syncthreads();
  mx = fmaxf(fmaxf(redm[0], redm[1]), fmaxf(redm[2], redm[3]));

  float sum = 0.f;
#pragma unroll
  for (int k = 0; k < 8; ++k) {
    v[k] = __expf(v[k] - mx);
    sum += v[k];
  }
#pragma unroll
  for (int off = 1; off < 64; off <<= 1) sum += __shfl_xor(sum, off);
  __shared__ float reds[4];
  if ((tid & 63) == 0) reds[tid >> 6] = sum;
  __syncthreads();
  sum = reds[0] + reds[1] + reds[2] + reds[3];
  float inv = 1.0f / sum;
#pragma unroll
  for (int k = 0; k < 8; ++k) p[(size_t)t * N_DIM + tid + k * 256] = v[k] * inv;
}

// ---------------- k3: t-chunked streaming output (rolling window) --------
#define TC 16
__global__ __launch_bounds__(256) void out_kernel(const float* __restrict__ x,
                                                  const float* __restrict__ p,
                                                  float* __restrict__ out) {
  const int gid = blockIdx.x * 256 + threadIdx.x;  // 131072 = 2048 * 64
  const int n = gid >> 6;
  const int d4 = gid & 63;
  const size_t base = (size_t)n * D_DIM + d4 * 4;
  const size_t tstride = (size_t)N_DIM * D_DIM;
  const int t0 = blockIdx.y * TC;

  float4 x0 = {}, x1 = {}, x2 = {};
  float p0 = 0.f, p1 = 0.f, p2 = 0.f;
  if (t0 > 0) {  // preload 3-slice history
    x0 = *(const float4*)(x + (size_t)(t0 - 3) * tstride + base);
    x1 = *(const float4*)(x + (size_t)(t0 - 2) * tstride + base);
    x2 = *(const float4*)(x + (size_t)(t0 - 1) * tstride + base);
    p0 = p[(size_t)(t0 - 3) * N_DIM + n];
    p1 = p[(size_t)(t0 - 2) * N_DIM + n];
    p2 = p[(size_t)(t0 - 1) * N_DIM + n];
  }
#pragma unroll
  for (int tt = 0; tt < TC; ++tt) {
    const int t = t0 + tt;
    float4 xc = {};
    if (tt < TC - 1) xc = *(const float4*)(x + (size_t)t * tstride + base);
    float4 o;
    if (t >= 3) {
      o.x = p0 * x0.x + p1 * x1.x + p2 * x2.x;
      o.y = p0 * x0.y + p1 * x1.y + p2 * x2.y;
      o.z = p0 * x0.z + p1 * x1.z + p2 * x2.z;
      o.w = p0 * x0.w + p1 * x1.w + p2 * x2.w;
    } else {
      o = xc;  // pass-through (only reachable for tt<3, xc loaded)
    }
    *(float4*)(out + (size_t)t * tstride + base) = o;
    x0 = x1; x1 = x2; x2 = xc;
    p0 = p1; p1 = p2;
    if (tt < TC - 1) p2 = p[(size_t)t * N_DIM + n];  // t <= 126 always here
  }
}

extern "C" void kernel_launch(void* const* d_in, const int* in_sizes, int n_in,
                              void* d_out, int out_size, void* d_ws, size_t ws_size,
                              hipStream_t stream) {
  const float* x = (const float*)d_in[0];     // (128, 2048, 256) fp32
  const float* W = (const float*)d_in[1];     // (256, 256) fp32
  const float* proj = (const float*)d_in[2];  // (256, 1) fp32
  float* out = (float*)d_out;

  char* ws = (char*)d_ws;
  short* Wt = (short*)ws;                      // 65536 bf16 = 128 KB
  float* s = (float*)(ws + 131072);            // 260096 f32 ~ 1 MB
  float* p = (float*)(ws + 131072 + 1040384);  // 260096 f32 ~ 1 MB

  hipLaunchKernelGGL(prep_kernel, dim3(256), dim3(256), 0, stream, W, Wt);

  // k1: s[t,n] = sum_e proj[e]*tanh((x[t] @ W)[n,e])  (s fully written, no memset)
  hipLaunchKernelGGL(gemm_s_kernel, dim3(M_TOT / 64), dim3(256), 0, stream,
                     x, Wt, proj, s);

  hipLaunchKernelGGL(softmax_kernel, dim3(TS), dim3(256), 0, stream, s, p);

  hipLaunchKernelGGL(out_kernel, dim3((N_DIM * 64) / 256, T_DIM / TC), dim3(256), 0,
                     stream, x, p, out);
}